// Round 1
// baseline (515.900 us; speedup 1.0000x reference)
//
#include <hip/hip_runtime.h>
#include <hip/hip_bf16.h>

// Problem constants (from reference): T=512 tokens, D=2048 hidden, E=64 experts,
// K=8 top-k, F=768 intermediate.
#define T_TOK 512
#define D_DIM 2048
#define E_NUM 64
#define K_TOP 8
#define F_DIM 768

typedef __bf16 bf16x8 __attribute__((ext_vector_type(8)));
typedef float  f32x4  __attribute__((ext_vector_type(4)));

// ---------------- workspace layout (bytes) ----------------
// cnt    : int[64]            @ 0
// ids    : int[64*512]        @ 4096        (pair row ids per expert, filled 0..cnt[e))
// pair_w : float[4096]        @ 139264      (renormalized top-k weight per pair row t*8+k)
// H      : bf16[4096*768]     @ 262144      (silu(g)*u per pair row)
// Y      : bf16[4096*2048]    @ 8388608     (down-proj per pair row)
// total ≈ 24 MB
#define WS_IDS   4096
#define WS_PW    139264
#define WS_H     262144
#define WS_Y     8388608

__device__ __forceinline__ uint4 pack8(float4 a, float4 b) {
    bf16x8 r;
    r[0] = (__bf16)a.x; r[1] = (__bf16)a.y; r[2] = (__bf16)a.z; r[3] = (__bf16)a.w;
    r[4] = (__bf16)b.x; r[5] = (__bf16)b.y; r[6] = (__bf16)b.z; r[7] = (__bf16)b.w;
    return __builtin_bit_cast(uint4, r);
}

__global__ void zero_cnt_kernel(int* __restrict__ cnt) {
    if (threadIdx.x < E_NUM) cnt[threadIdx.x] = 0;
}

// ---------------- router: logits -> softmax -> top-8 -> renorm ----------------
// One block per token. 256 threads: thread (c,e) computes quarter-dot for expert e.
// Renormalized top-k of softmax == softmax over the top-k logits (exact identity).
__global__ __launch_bounds__(256) void router_kernel(
        const float* __restrict__ x, const float* __restrict__ gw,
        float* __restrict__ pair_w, int* __restrict__ cnt, int* __restrict__ ids) {
    const int t   = blockIdx.x;
    const int tid = threadIdx.x;
    const int e   = tid & 63;
    const int c   = tid >> 6;
    const float* xr = x + (size_t)t * D_DIM;
    const int k0 = c * (D_DIM / 4);
    float s = 0.f;
    #pragma unroll 8
    for (int k = 0; k < D_DIM / 4; k++) {
        s += xr[k0 + k] * gw[(size_t)(k0 + k) * E_NUM + e];
    }
    __shared__ float part[4][64];
    part[c][e] = s;
    __syncthreads();
    if (tid < 64) {  // first wave only; lane == e
        float logit = part[0][e] + part[1][e] + part[2][e] + part[3][e];
        float cur = logit;
        float selV[8]; int selE[8];
        #pragma unroll
        for (int i = 0; i < 8; i++) {
            float bv = cur; int bi = e;
            #pragma unroll
            for (int off = 32; off > 0; off >>= 1) {
                float ov = __shfl_xor(bv, off);
                int   oi = __shfl_xor(bi, off);
                if (ov > bv || (ov == bv && oi < bi)) { bv = ov; bi = oi; }
            }
            selV[i] = bv; selE[i] = bi;
            if (e == bi) cur = -INFINITY;
        }
        const float m = selV[0];
        float sum = 0.f;
        #pragma unroll
        for (int i = 0; i < 8; i++) sum += __expf(selV[i] - m);
        float myW = 0.f; int myE = 0;
        #pragma unroll
        for (int i = 0; i < 8; i++) {
            if (e == i) { myW = __expf(selV[i] - m) / sum; myE = selE[i]; }
        }
        if (e < 8) {
            pair_w[t * K_TOP + e] = myW;
            int pos = atomicAdd(&cnt[myE], 1);
            ids[myE * T_TOK + pos] = t * K_TOP + e;  // encodes token = id>>3
        }
    }
}

// ---------------- mlp1: H[pair] = silu(X@Wg) * (X@Wu), bf16 ----------------
// Block: 256 thr = 4 waves, 1x4 over N. BM=128 (covers n_e in one pass -> each
// weight element read exactly once), BN=64 (wave owns 16 F-cols), BK=32.
// A (gathered X rows) -> bf16 -> LDS in fragment layout [kb][row] 16B groups.
// B (Wg/Wu) -> per-lane k-gather dword loads direct to regs (no reuse -> no LDS).
// MFMA frag maps (16x16x32 bf16): A[m][k]: m=lane&15, k=8*(lane>>4)+i
//                                 B[k][n]: n=lane&15, k=8*(lane>>4)+i
//                                 D[row][col]: col=lane&15, row=4*(lane>>4)+r  [m89]
__global__ __launch_bounds__(256, 2) void mlp1_kernel(
        const float* __restrict__ x,
        const float* __restrict__ w_gate, const float* __restrict__ w_up,
        const int* __restrict__ cnt, const int* __restrict__ ids,
        __bf16* __restrict__ H) {
    const int e     = blockIdx.z;
    const int mtile = blockIdx.y;
    const int ftile = blockIdx.x;   // 12 tiles of 64
    const int n = cnt[e];
    if (mtile * 128 >= n) return;

    const int tid  = threadIdx.x;
    const int lane = tid & 63;
    const int w    = tid >> 6;

    __shared__ uint4 ldsA[2][512];  // [kb*128 + row], double buffered, 16 KB

    // A staging: thread owns one row, two kb groups {skb0, skb0+2}
    const int srow = tid & 127;
    const int skb0 = tid >> 7;      // 0 or 1
    const int pos  = mtile * 128 + srow;
    const int tok  = (pos < n) ? (ids[e * T_TOK + pos] >> 3) : 0;
    const float4* xrow = (const float4*)(x + (size_t)tok * D_DIM);

    // B bases (krow folded in)
    const int fcol = ftile * 64 + w * 16 + (lane & 15);
    const int krow = 8 * (lane >> 4);
    const float* bg = w_gate + (size_t)e * D_DIM * F_DIM + (size_t)krow * F_DIM + fcol;
    const float* bu = w_up   + (size_t)e * D_DIM * F_DIM + (size_t)krow * F_DIM + fcol;

    f32x4 accg[8], accu[8];
    #pragma unroll
    for (int m = 0; m < 8; m++) {
        accg[m][0]=0.f; accg[m][1]=0.f; accg[m][2]=0.f; accg[m][3]=0.f;
        accu[m][0]=0.f; accu[m][1]=0.f; accu[m][2]=0.f; accu[m][3]=0.f;
    }

    // prologue: stage ks=0 into buf 0
    {
        float4 v0 = xrow[skb0 * 2];
        float4 v1 = xrow[skb0 * 2 + 1];
        float4 v2 = xrow[(skb0 + 2) * 2];
        float4 v3 = xrow[(skb0 + 2) * 2 + 1];
        ldsA[0][tid]       = pack8(v0, v1);
        ldsA[0][256 + tid] = pack8(v2, v3);
    }
    __syncthreads();

    const int abase = (lane >> 4) * 128 + (lane & 15);
    for (int ks = 0; ks < 64; ks++) {
        const int cur   = ks & 1;
        const int kbase = ks * 32;
        // B loads (current step) -> regs
        float bgv[8], buv[8];
        #pragma unroll
        for (int i = 0; i < 8; i++) {
            const int off = (kbase + i) * F_DIM;
            bgv[i] = bg[off];
            buv[i] = bu[off];
        }
        // A prefetch for ks+1 (issue before MFMA)
        float4 v0, v1, v2, v3;
        if (ks + 1 < 64) {
            const int kb8 = (ks + 1) * 8;  // float4 index base
            v0 = xrow[kb8 + skb0 * 2];
            v1 = xrow[kb8 + skb0 * 2 + 1];
            v2 = xrow[kb8 + (skb0 + 2) * 2];
            v3 = xrow[kb8 + (skb0 + 2) * 2 + 1];
        }
        // cvt B
        bf16x8 bgf, buf8;
        #pragma unroll
        for (int i = 0; i < 8; i++) { bgf[i] = (__bf16)bgv[i]; buf8[i] = (__bf16)buv[i]; }
        // MFMA: A shared between gate and up
        #pragma unroll
        for (int m = 0; m < 8; m++) {
            bf16x8 af = __builtin_bit_cast(bf16x8, ldsA[cur][abase + m * 16]);
            accg[m] = __builtin_amdgcn_mfma_f32_16x16x32_bf16(af, bgf,  accg[m], 0, 0, 0);
            accu[m] = __builtin_amdgcn_mfma_f32_16x16x32_bf16(af, buf8, accu[m], 0, 0, 0);
        }
        // write staged A for ks+1
        if (ks + 1 < 64) {
            ldsA[cur ^ 1][tid]       = pack8(v0, v1);
            ldsA[cur ^ 1][256 + tid] = pack8(v2, v3);
        }
        __syncthreads();
    }

    // epilogue: h = silu(g)*u -> H[pair_row][f]
    #pragma unroll
    for (int m = 0; m < 8; m++) {
        #pragma unroll
        for (int r = 0; r < 4; r++) {
            const int p = mtile * 128 + m * 16 + (lane >> 4) * 4 + r;
            if (p < n) {
                const int rid = ids[e * T_TOK + p];
                const float g = accg[m][r], u = accu[m][r];
                const float h = (g / (1.f + __expf(-g))) * u;
                H[(size_t)rid * F_DIM + fcol] = (__bf16)h;
            }
        }
    }
}

// ---------------- mlp2: Y[pair] = H @ Wd, bf16 ----------------
// Same structure; A = H rows (already bf16, no cvt), BK=32 over F (24 steps),
// BN=64 over D (32 tiles).
__global__ __launch_bounds__(256, 2) void mlp2_kernel(
        const __bf16* __restrict__ H, const float* __restrict__ w_down,
        const int* __restrict__ cnt, const int* __restrict__ ids,
        __bf16* __restrict__ Y) {
    const int e     = blockIdx.z;
    const int mtile = blockIdx.y;
    const int dtile = blockIdx.x;   // 32 tiles of 64
    const int n = cnt[e];
    if (mtile * 128 >= n) return;

    const int tid  = threadIdx.x;
    const int lane = tid & 63;
    const int w    = tid >> 6;

    __shared__ uint4 ldsA[2][512];

    const int srow = tid & 127;
    const int skb0 = tid >> 7;
    const int pos  = mtile * 128 + srow;
    const int rid0 = (pos < n) ? ids[e * T_TOK + pos] : 0;
    const uint4* hr = (const uint4*)(H + (size_t)rid0 * F_DIM);  // 16B = 8 bf16

    const int dcol = dtile * 64 + w * 16 + (lane & 15);
    const int krow = 8 * (lane >> 4);
    const float* bd = w_down + (size_t)e * F_DIM * D_DIM + (size_t)krow * D_DIM + dcol;

    f32x4 acc[8];
    #pragma unroll
    for (int m = 0; m < 8; m++) { acc[m][0]=0.f; acc[m][1]=0.f; acc[m][2]=0.f; acc[m][3]=0.f; }

    // prologue
    ldsA[0][tid]       = hr[skb0];
    ldsA[0][256 + tid] = hr[skb0 + 2];
    __syncthreads();

    const int abase = (lane >> 4) * 128 + (lane & 15);
    for (int ks = 0; ks < 24; ks++) {
        const int cur   = ks & 1;
        const int kbase = ks * 32;
        float bdv[8];
        #pragma unroll
        for (int i = 0; i < 8; i++) bdv[i] = bd[(kbase + i) * D_DIM];
        uint4 a0, a1;
        if (ks + 1 < 24) {
            a0 = hr[(ks + 1) * 4 + skb0];
            a1 = hr[(ks + 1) * 4 + skb0 + 2];
        }
        bf16x8 bdf;
        #pragma unroll
        for (int i = 0; i < 8; i++) bdf[i] = (__bf16)bdv[i];
        #pragma unroll
        for (int m = 0; m < 8; m++) {
            bf16x8 af = __builtin_bit_cast(bf16x8, ldsA[cur][abase + m * 16]);
            acc[m] = __builtin_amdgcn_mfma_f32_16x16x32_bf16(af, bdf, acc[m], 0, 0, 0);
        }
        if (ks + 1 < 24) {
            ldsA[cur ^ 1][tid]       = a0;
            ldsA[cur ^ 1][256 + tid] = a1;
        }
        __syncthreads();
    }

    #pragma unroll
    for (int m = 0; m < 8; m++) {
        #pragma unroll
        for (int r = 0; r < 4; r++) {
            const int p = mtile * 128 + m * 16 + (lane >> 4) * 4 + r;
            if (p < n) {
                const int rid = ids[e * T_TOK + p];
                Y[(size_t)rid * D_DIM + dcol] = (__bf16)acc[m][r];
            }
        }
    }
}

// ---------------- combine: out[t] = sum_k w[t,k] * Y[t*8+k] ----------------
// Fixed summation order -> bitwise deterministic; fully overwrites d_out.
__global__ __launch_bounds__(256) void combine_kernel(
        const __bf16* __restrict__ Y, const float* __restrict__ pw,
        float* __restrict__ out) {
    const int t   = blockIdx.x;
    const int tid = threadIdx.x;
    const int d0  = tid * 8;
    float acc[8];
    #pragma unroll
    for (int j = 0; j < 8; j++) acc[j] = 0.f;
    #pragma unroll
    for (int k = 0; k < K_TOP; k++) {
        const float wgt = pw[t * K_TOP + k];
        bf16x8 v = *(const bf16x8*)(Y + (size_t)(t * K_TOP + k) * D_DIM + d0);
        #pragma unroll
        for (int j = 0; j < 8; j++) acc[j] += wgt * (float)v[j];
    }
    #pragma unroll
    for (int j = 0; j < 8; j++) out[(size_t)t * D_DIM + d0 + j] = acc[j];
}

extern "C" void kernel_launch(void* const* d_in, const int* in_sizes, int n_in,
                              void* d_out, int out_size, void* d_ws, size_t ws_size,
                              hipStream_t stream) {
    const float* x      = (const float*)d_in[0];
    const float* gw     = (const float*)d_in[1];
    const float* w_gate = (const float*)d_in[2];
    const float* w_up   = (const float*)d_in[3];
    const float* w_down = (const float*)d_in[4];
    float* out = (float*)d_out;

    char* ws = (char*)d_ws;
    int*    cnt = (int*)(ws);
    int*    ids = (int*)(ws + WS_IDS);
    float*  pw  = (float*)(ws + WS_PW);
    __bf16* H   = (__bf16*)(ws + WS_H);
    __bf16* Y   = (__bf16*)(ws + WS_Y);

    zero_cnt_kernel<<<1, 64, 0, stream>>>(cnt);
    router_kernel<<<T_TOK, 256, 0, stream>>>(x, gw, pw, cnt, ids);
    mlp1_kernel<<<dim3(F_DIM / 64, 4, E_NUM), 256, 0, stream>>>(x, w_gate, w_up, cnt, ids, H);
    mlp2_kernel<<<dim3(D_DIM / 64, 4, E_NUM), 256, 0, stream>>>(H, w_down, cnt, ids, Y);
    combine_kernel<<<T_TOK, 256, 0, stream>>>(Y, pw, out);
}